// Round 3
// baseline (1768.242 us; speedup 1.0000x reference)
//
#include <hip/hip_runtime.h>
#include <hip/hip_bf16.h>

typedef unsigned short u16;
typedef unsigned int   u32;
typedef __bf16 bf16x8 __attribute__((ext_vector_type(8)));
typedef float  f32x4  __attribute__((ext_vector_type(4)));

#define NB 4
#define T_ 2048
#define D_ 1024
#define H_ 16
#define DH 64
#define M_ (NB * T_)   // 8192 rows
#define MASK_NEG (-1.0e30f)

__device__ __forceinline__ float bf2f(u16 u) {
    union { u32 i; float f; } v; v.i = ((u32)u) << 16; return v.f;
}
__device__ __forceinline__ u16 f2bf(float f) {
    union { float fl; u32 i; } v; v.fl = f;
    u32 r = v.i + 0x7fff + ((v.i >> 16) & 1);
    return (u16)(r >> 16);
}

// ---------------------------------------------------------- dtype detector
// Wave-uniform: is the buffer f32 (1) or bf16 (0)?  Viewing f32 data as u16
// halfwords makes every low half a bf16 with ~uniform-random exponent bits
// (~50% land in the "weird" ranges incl. inf/NaN); genuine bf16 activations/
// weights (|v| < 2^64, > 2^-64) hit none. Scan first 256 halfwords.
__device__ __forceinline__ int detect_f32(const u16* p) {
    int weird = 0;
    const int lane = threadIdx.x & 63;
    #pragma unroll
    for (int i = 0; i < 4; ++i) {
        const u16 u = p[lane * 4 + i];
        const int e = (u >> 7) & 0xFF;
        weird += (e == 0xFF || (e >= 0x01 && e <= 0x3F) || (e >= 0xC0 && e <= 0xFE));
    }
    #pragma unroll
    for (int off = 32; off; off >>= 1) weird += __shfl_xor(weird, off);
    return weird >= 16;
}

// int32/int64-tolerant sequence-length read (all values must be in [1,T] in
// the int32 view; otherwise interpret as int64).
__device__ __forceinline__ int read_len(const void* raw, int b) {
    const int* a32 = (const int*)raw;
    bool ok32 = true;
    #pragma unroll
    for (int i = 0; i < NB; ++i) {
        const int v = a32[i];
        if (v < 1 || v > T_) ok32 = false;
    }
    int v = ok32 ? a32[b] : (int)((const long long*)raw)[b];
    return min(max(v, 1), T_);
}

// ---------------------------------------------------------------- LayerNorm
__global__ __launch_bounds__(256) void ln_kernel(const void* __restrict__ xraw,
                                                 const void* __restrict__ graw,
                                                 const void* __restrict__ braw,
                                                 u16* __restrict__ h) {
    const int row = blockIdx.x;
    const int tid = threadIdx.x;
    const int isf = detect_f32((const u16*)xraw);

    float xv[4];
    if (isf) {
        const float* xr = (const float*)xraw + (size_t)row * D_;
        *(float4*)xv = *(const float4*)&xr[tid * 4];
    } else {
        const u16* xr = (const u16*)xraw + (size_t)row * D_;
        u16 loc[4] __attribute__((aligned(8)));
        *(uint2*)loc = *(const uint2*)&xr[tid * 4];
        #pragma unroll
        for (int i = 0; i < 4; ++i) xv[i] = bf2f(loc[i]);
    }

    float s = xv[0] + xv[1] + xv[2] + xv[3];
    float q = xv[0]*xv[0] + xv[1]*xv[1] + xv[2]*xv[2] + xv[3]*xv[3];

    #pragma unroll
    for (int off = 32; off; off >>= 1) {
        s += __shfl_xor(s, off);
        q += __shfl_xor(q, off);
    }
    __shared__ float red[8];
    const int wave = tid >> 6, lane = tid & 63;
    if (lane == 0) { red[wave] = s; red[4 + wave] = q; }
    __syncthreads();
    s = red[0] + red[1] + red[2] + red[3];
    q = red[4] + red[5] + red[6] + red[7];

    const float mean = s * (1.0f / D_);
    const float var  = q * (1.0f / D_) - mean * mean;
    const float rs   = rsqrtf(var + 1e-5f);

    u16 o[4] __attribute__((aligned(8)));
    #pragma unroll
    for (int i = 0; i < 4; ++i) {
        const int c = tid * 4 + i;
        const float gv = isf ? ((const float*)graw)[c] : bf2f(((const u16*)graw)[c]);
        const float bv = isf ? ((const float*)braw)[c] : bf2f(((const u16*)braw)[c]);
        o[i] = f2bf((xv[i] - mean) * rs * gv + bv);
    }
    *(uint2*)&h[(size_t)row * D_ + tid * 4] = *(uint2*)o;
}

// ---------------------------------------------------------------- GEMM
// C[M x 1024] = A[M x 1024](bf16, internal) * B[1024 x 1024](f32 or bf16) + bias
// Block tile 128(M) x 64(N), 4 waves, each wave 32x64 via 8 mfma 16x16x32.
// mode 0: row-major store to d_out (format follows weight dtype)
// mode 1: scatter (N,H,T,DH) bf16 (V) ; mode 2: scatter + RoPE (Q,K)
__global__ __launch_bounds__(256) void gemm_kernel(const u16* __restrict__ A,
                                                   const void* __restrict__ Braw,
                                                   const void* __restrict__ biasraw,
                                                   void* __restrict__ out,
                                                   const int mode) {
    __shared__ __align__(16) u16 As[128 * 32];
    __shared__ __align__(16) u16 Bs[64 * 32];

    const int tid   = threadIdx.x;
    const int ntile = blockIdx.x * 64;
    const int mtile = blockIdx.y * 128;
    const int wave  = tid >> 6;
    const int lane  = tid & 63;
    const int quad  = lane >> 4;
    const int lr    = lane & 15;

    const int isf = detect_f32((const u16*)Braw);
    const float* Bf = (const float*)Braw;
    const u16*   Bu = (const u16*)Braw;

    f32x4 acc[2][4];
    #pragma unroll
    for (int s = 0; s < 2; ++s)
        #pragma unroll
        for (int n = 0; n < 4; ++n)
            acc[s][n] = (f32x4){0.f, 0.f, 0.f, 0.f};

    const int ar  = tid >> 1;           // 0..127
    const int akb = (tid & 1) * 16;     // 0 or 16
    const int bn  = tid & 63;           // 0..63
    const int bkb = (tid >> 6) * 8;     // 0,8,16,24
    const u16* Arow = A + (size_t)(mtile + ar) * D_ + akb;
    const size_t bcol0 = (size_t)bkb * D_ + ntile + bn;

    for (int k0 = 0; k0 < D_; k0 += 32) {
        // stage A (coalesced 16B loads)
        *(uint4*)&As[ar * 32 + akb]     = *(const uint4*)(Arow + k0);
        *(uint4*)&As[ar * 32 + akb + 8] = *(const uint4*)(Arow + k0 + 8);
        // stage B transposed: Bs[n][k]
        u16 tmp[8] __attribute__((aligned(16)));
        if (isf) {
            #pragma unroll
            for (int j = 0; j < 8; ++j) tmp[j] = f2bf(Bf[bcol0 + (size_t)(k0 + j) * D_]);
        } else {
            #pragma unroll
            for (int j = 0; j < 8; ++j) tmp[j] = Bu[bcol0 + (size_t)(k0 + j) * D_];
        }
        *(uint4*)&Bs[bn * 32 + bkb] = *(uint4*)tmp;
        __syncthreads();

        const int mbase = wave * 32;
        bf16x8 af0 = *(const bf16x8*)&As[(mbase +      lr) * 32 + quad * 8];
        bf16x8 af1 = *(const bf16x8*)&As[(mbase + 16 + lr) * 32 + quad * 8];
        #pragma unroll
        for (int nt = 0; nt < 4; ++nt) {
            bf16x8 bf = *(const bf16x8*)&Bs[(nt * 16 + lr) * 32 + quad * 8];
            acc[0][nt] = __builtin_amdgcn_mfma_f32_16x16x32_bf16(af0, bf, acc[0][nt], 0, 0, 0);
            acc[1][nt] = __builtin_amdgcn_mfma_f32_16x16x32_bf16(af1, bf, acc[1][nt], 0, 0, 0);
        }
        __syncthreads();
    }

    // epilogue: C row = quad*4+reg, col = lr  (per 16x16 tile)
    #pragma unroll
    for (int s2 = 0; s2 < 2; ++s2) {
        #pragma unroll
        for (int nt = 0; nt < 4; ++nt) {
            const int ncol = ntile + nt * 16 + lr;
            const float bv = isf ? ((const float*)biasraw)[ncol]
                                 : bf2f(((const u16*)biasraw)[ncol]);
            #pragma unroll
            for (int r = 0; r < 4; ++r) {
                const int mrow = mtile + wave * 32 + s2 * 16 + quad * 4 + r;
                float v = acc[s2][nt][r] + bv;
                if (mode == 2) {
                    const float other = __shfl_xor(v, 1);
                    const int d = ncol & (DH - 1);
                    const int t = mrow & (T_ - 1);
                    const int i = d >> 1;
                    // inv_freq = 10000^(-i/32) = 2^(-i*log2(1e4)/32)
                    const float inv = exp2f(-(float)i * 0.41524101186092f);
                    const float ang = (float)t * inv;
                    const float cv = cosf(ang), sv = sinf(ang);
                    v = (d & 1) ? (other * sv + v * cv) : (v * cv - other * sv);
                }
                if (mode == 0) {
                    if (isf) ((float*)out)[(size_t)mrow * D_ + ncol] = v;
                    else     ((u16*)out)[(size_t)mrow * D_ + ncol] = f2bf(v);
                } else {
                    const int d  = ncol & (DH - 1);
                    const int hh = ncol >> 6;
                    const int t  = mrow & (T_ - 1);
                    const int bb = mrow >> 11;
                    ((u16*)out)[(((size_t)(bb * H_ + hh) * T_) + t) * DH + d] = f2bf(v);
                }
            }
        }
    }
}

// ---------------------------------------------------------------- attention
// Flash-style, VALU f32. Block = 256 thr, one 64-row Q tile of one (b,h).
// All masking uses a large FINITE negative so no inf arithmetic can occur.
__global__ __launch_bounds__(256) void attn_kernel(const u16* __restrict__ Q,
                                                   const u16* __restrict__ K,
                                                   const u16* __restrict__ V,
                                                   const void* __restrict__ lensraw,
                                                   u16* __restrict__ ctx) {
    __shared__ __align__(16) float Qs[64 * 66];
    __shared__ __align__(16) float KVs[64 * 66];
    __shared__ __align__(16) float Ps[64 * 66];

    const int tid = threadIdx.x;
    const int ti  = tid >> 4;       // 0..15
    const int tj  = tid & 15;       // 0..15
    const int i0  = ti * 4;
    const int j0  = tj * 4;
    const int bh  = blockIdx.y;
    const int qs  = blockIdx.x * 64;
    const int b   = bh >> 4;
    const int hh  = bh & 15;
    const int len = read_len(lensraw, b);
    const size_t base = (size_t)bh * T_ * DH;

    // stage Q, pre-scaled by 1/sqrt(DH)
    {
        const int jr = tid >> 2;
        const int db = (tid & 3) * 16;
        u16 t16[16] __attribute__((aligned(16)));
        *(uint4*)&t16[0] = *(const uint4*)&Q[base + (size_t)(qs + jr) * DH + db];
        *(uint4*)&t16[8] = *(const uint4*)&Q[base + (size_t)(qs + jr) * DH + db + 8];
        #pragma unroll
        for (int e = 0; e < 16; ++e) Qs[jr * 66 + db + e] = bf2f(t16[e]) * 0.125f;
    }

    float m[4], l[4], acc[4][4];
    #pragma unroll
    for (int r = 0; r < 4; ++r) {
        m[r] = MASK_NEG; l[r] = 0.f;
        #pragma unroll
        for (int c = 0; c < 4; ++c) acc[r][c] = 0.f;
    }

    const int smax = min(qs + 63, len - 1);
    const int ktn  = smax / 64 + 1;

    for (int kt = 0; kt < ktn; ++kt) {
        const int ks = kt * 64;
        __syncthreads();
        // stage K (f32)
        {
            const int jr = tid >> 2;
            const int db = (tid & 3) * 16;
            u16 t16[16] __attribute__((aligned(16)));
            *(uint4*)&t16[0] = *(const uint4*)&K[base + (size_t)(ks + jr) * DH + db];
            *(uint4*)&t16[8] = *(const uint4*)&K[base + (size_t)(ks + jr) * DH + db + 8];
            #pragma unroll
            for (int e = 0; e < 16; ++e) KVs[jr * 66 + db + e] = bf2f(t16[e]);
        }
        __syncthreads();

        // scores 4x4
        float s4[4][4];
        #pragma unroll
        for (int r = 0; r < 4; ++r)
            #pragma unroll
            for (int c = 0; c < 4; ++c) s4[r][c] = 0.f;
        for (int d = 0; d < 64; d += 2) {
            float2 qv[4], kv[4];
            #pragma unroll
            for (int r = 0; r < 4; ++r) qv[r] = *(const float2*)&Qs[(i0 + r) * 66 + d];
            #pragma unroll
            for (int c = 0; c < 4; ++c) kv[c] = *(const float2*)&KVs[(j0 + c) * 66 + d];
            #pragma unroll
            for (int r = 0; r < 4; ++r)
                #pragma unroll
                for (int c = 0; c < 4; ++c)
                    s4[r][c] += qv[r].x * kv[c].x + qv[r].y * kv[c].y;
        }

        // cap, mask, online softmax (reduce over 16 lanes of a row group)
        #pragma unroll
        for (int r = 0; r < 4; ++r) {
            const int trow = qs + i0 + r;
            float mx = MASK_NEG;
            #pragma unroll
            for (int c = 0; c < 4; ++c) {
                float sc = 30.0f * tanhf(s4[r][c] * (1.0f / 30.0f));
                const int scol = ks + j0 + c;
                sc = (scol > trow || scol >= len) ? MASK_NEG : sc;
                s4[r][c] = sc;
                mx = fmaxf(mx, sc);
            }
            #pragma unroll
            for (int off = 1; off < 16; off <<= 1) mx = fmaxf(mx, __shfl_xor(mx, off, 16));
            const float mn = fmaxf(m[r], mx);
            float p[4], ps = 0.f;
            #pragma unroll
            for (int c = 0; c < 4; ++c) { p[c] = expf(s4[r][c] - mn); ps += p[c]; }
            #pragma unroll
            for (int off = 1; off < 16; off <<= 1) ps += __shfl_xor(ps, off, 16);
            const float alpha = expf(m[r] - mn);   // <= 1, finite
            m[r] = mn;
            l[r] = l[r] * alpha + ps;
            #pragma unroll
            for (int c = 0; c < 4; ++c) acc[r][c] *= alpha;
            #pragma unroll
            for (int c = 0; c < 4; ++c) Ps[(i0 + r) * 66 + j0 + c] = p[c];
        }
        __syncthreads();

        // stage V into same buffer (K no longer needed)
        {
            const int jr = tid >> 2;
            const int db = (tid & 3) * 16;
            u16 t16[16] __attribute__((aligned(16)));
            *(uint4*)&t16[0] = *(const uint4*)&V[base + (size_t)(ks + jr) * DH + db];
            *(uint4*)&t16[8] = *(const uint4*)&V[base + (size_t)(ks + jr) * DH + db + 8];
            #pragma unroll
            for (int e = 0; e < 16; ++e) KVs[jr * 66 + db + e] = bf2f(t16[e]);
        }
        __syncthreads();

        // PV: acc[r][c] += sum_j P[i0+r][j] * V[j][j0+c]
        for (int j = 0; j < 64; j += 2) {
            float2 pv[4];
            #pragma unroll
            for (int r = 0; r < 4; ++r) pv[r] = *(const float2*)&Ps[(i0 + r) * 66 + j];
            const float2 va0 = *(const float2*)&KVs[j * 66 + j0];
            const float2 va1 = *(const float2*)&KVs[j * 66 + j0 + 2];
            const float2 vb0 = *(const float2*)&KVs[(j + 1) * 66 + j0];
            const float2 vb1 = *(const float2*)&KVs[(j + 1) * 66 + j0 + 2];
            #pragma unroll
            for (int r = 0; r < 4; ++r) {
                acc[r][0] += pv[r].x * va0.x + pv[r].y * vb0.x;
                acc[r][1] += pv[r].x * va0.y + pv[r].y * vb0.y;
                acc[r][2] += pv[r].x * va1.x + pv[r].y * vb1.x;
                acc[r][3] += pv[r].x * va1.y + pv[r].y * vb1.y;
            }
        }
    }

    // write ctx (N,T,H*DH) row-major, bf16
    #pragma unroll
    for (int r = 0; r < 4; ++r) {
        const float inv_l = (l[r] > 0.f) ? (1.0f / l[r]) : 0.f;
        #pragma unroll
        for (int c = 0; c < 4; ++c) {
            ctx[(size_t)(b * T_ + qs + i0 + r) * D_ + hh * DH + j0 + c] =
                f2bf(acc[r][c] * inv_l);
        }
    }
}

// ---------------------------------------------------------------- launch
extern "C" void kernel_launch(void* const* d_in, const int* in_sizes, int n_in,
                              void* d_out, int out_size, void* d_ws, size_t ws_size,
                              hipStream_t stream) {
    // ws layout (exactly 64 MB): [h: 16MB][q: 16MB][k: 16MB][v: 16MB]
    u16* h = (u16*)d_ws;
    const size_t MD = (size_t)M_ * D_;
    u16* q = h + MD;
    u16* k = q + MD;
    u16* v = k + MD;

    ln_kernel<<<M_, 256, 0, stream>>>(d_in[0], d_in[1], d_in[2], h);

    dim3 ggrid(D_ / 64, M_ / 128);
    gemm_kernel<<<ggrid, 256, 0, stream>>>(h, d_in[3], d_in[4], q, 2);
    gemm_kernel<<<ggrid, 256, 0, stream>>>(h, d_in[5], d_in[6], k, 2);
    gemm_kernel<<<ggrid, 256, 0, stream>>>(h, d_in[7], d_in[8], v, 1);

    attn_kernel<<<dim3(T_ / 64, NB * H_), 256, 0, stream>>>(q, k, v, d_in[13], h);

    gemm_kernel<<<ggrid, 256, 0, stream>>>(h, d_in[9], d_in[10], d_out, 0);
}

// Round 4
// 601.510 us; speedup vs baseline: 2.9397x; 2.9397x over previous
//
#include <hip/hip_runtime.h>
#include <hip/hip_bf16.h>

typedef unsigned short u16;
typedef unsigned int   u32;
typedef __bf16 bf16x8 __attribute__((ext_vector_type(8)));
typedef float  f32x4  __attribute__((ext_vector_type(4)));

#define NB 4
#define T_ 2048
#define D_ 1024
#define H_ 16
#define DH 64
#define M_ (NB * T_)   // 8192 rows
#define MASK_NEG (-1.0e30f)
#define PSTR 72        // padded LDS row stride (elements) for 64-wide tiles

__device__ __forceinline__ float bf2f(u16 u) {
    union { u32 i; float f; } v; v.i = ((u32)u) << 16; return v.f;
}
__device__ __forceinline__ u16 f2bf(float f) {
    union { float fl; u32 i; } v; v.fl = f;
    u32 r = v.i + 0x7fff + ((v.i >> 16) & 1);
    return (u16)(r >> 16);
}

// ---------------------------------------------------------- dtype detector
__device__ __forceinline__ int detect_f32(const u16* p) {
    int weird = 0;
    const int lane = threadIdx.x & 63;
    #pragma unroll
    for (int i = 0; i < 4; ++i) {
        const u16 u = p[lane * 4 + i];
        const int e = (u >> 7) & 0xFF;
        weird += (e == 0xFF || (e >= 0x01 && e <= 0x3F) || (e >= 0xC0 && e <= 0xFE));
    }
    #pragma unroll
    for (int off = 32; off; off >>= 1) weird += __shfl_xor(weird, off);
    return weird >= 16;
}

// int32/int64-tolerant sequence-length read
__device__ __forceinline__ int read_len(const void* raw, int b) {
    const int* a32 = (const int*)raw;
    bool ok32 = true;
    #pragma unroll
    for (int i = 0; i < NB; ++i) {
        const int v = a32[i];
        if (v < 1 || v > T_) ok32 = false;
    }
    int v = ok32 ? a32[b] : (int)((const long long*)raw)[b];
    return min(max(v, 1), T_);
}

// ---------------------------------------------------------------- LayerNorm
__global__ __launch_bounds__(256) void ln_kernel(const void* __restrict__ xraw,
                                                 const void* __restrict__ graw,
                                                 const void* __restrict__ braw,
                                                 u16* __restrict__ h) {
    const int row = blockIdx.x;
    const int tid = threadIdx.x;
    const int isf = detect_f32((const u16*)xraw);

    float xv[4];
    if (isf) {
        const float* xr = (const float*)xraw + (size_t)row * D_;
        *(float4*)xv = *(const float4*)&xr[tid * 4];
    } else {
        const u16* xr = (const u16*)xraw + (size_t)row * D_;
        u16 loc[4] __attribute__((aligned(8)));
        *(uint2*)loc = *(const uint2*)&xr[tid * 4];
        #pragma unroll
        for (int i = 0; i < 4; ++i) xv[i] = bf2f(loc[i]);
    }

    float s = xv[0] + xv[1] + xv[2] + xv[3];
    float q = xv[0]*xv[0] + xv[1]*xv[1] + xv[2]*xv[2] + xv[3]*xv[3];

    #pragma unroll
    for (int off = 32; off; off >>= 1) {
        s += __shfl_xor(s, off);
        q += __shfl_xor(q, off);
    }
    __shared__ float red[8];
    const int wave = tid >> 6, lane = tid & 63;
    if (lane == 0) { red[wave] = s; red[4 + wave] = q; }
    __syncthreads();
    s = red[0] + red[1] + red[2] + red[3];
    q = red[4] + red[5] + red[6] + red[7];

    const float mean = s * (1.0f / D_);
    const float var  = q * (1.0f / D_) - mean * mean;
    const float rs   = rsqrtf(var + 1e-5f);

    u16 o[4] __attribute__((aligned(8)));
    #pragma unroll
    for (int i = 0; i < 4; ++i) {
        const int c = tid * 4 + i;
        const float gv = isf ? ((const float*)graw)[c] : bf2f(((const u16*)graw)[c]);
        const float bv = isf ? ((const float*)braw)[c] : bf2f(((const u16*)braw)[c]);
        o[i] = f2bf((xv[i] - mean) * rs * gv + bv);
    }
    *(uint2*)&h[(size_t)row * D_ + tid * 4] = *(uint2*)o;
}

// ---------------------------------------------------------------- GEMM
// mode 0: row-major store to d_out (format follows weight dtype)
// mode 1: scatter V TRANSPOSED (N,H,DH,T)  [so attention PV B-frags are
//         contiguous-in-key ds_read_b128]
// mode 2: scatter (N,H,T,DH) + RoPE (Q,K)
__global__ __launch_bounds__(256) void gemm_kernel(const u16* __restrict__ A,
                                                   const void* __restrict__ Braw,
                                                   const void* __restrict__ biasraw,
                                                   void* __restrict__ out,
                                                   const int mode) {
    __shared__ __align__(16) u16 As[128 * 32];
    __shared__ __align__(16) u16 Bs[64 * 32];

    const int tid   = threadIdx.x;
    const int ntile = blockIdx.x * 64;
    const int mtile = blockIdx.y * 128;
    const int wave  = tid >> 6;
    const int lane  = tid & 63;
    const int quad  = lane >> 4;
    const int lr    = lane & 15;

    const int isf = detect_f32((const u16*)Braw);
    const float* Bf = (const float*)Braw;
    const u16*   Bu = (const u16*)Braw;

    f32x4 acc[2][4];
    #pragma unroll
    for (int s = 0; s < 2; ++s)
        #pragma unroll
        for (int n = 0; n < 4; ++n)
            acc[s][n] = (f32x4){0.f, 0.f, 0.f, 0.f};

    const int ar  = tid >> 1;
    const int akb = (tid & 1) * 16;
    const int bn  = tid & 63;
    const int bkb = (tid >> 6) * 8;
    const u16* Arow = A + (size_t)(mtile + ar) * D_ + akb;
    const size_t bcol0 = (size_t)bkb * D_ + ntile + bn;

    for (int k0 = 0; k0 < D_; k0 += 32) {
        *(uint4*)&As[ar * 32 + akb]     = *(const uint4*)(Arow + k0);
        *(uint4*)&As[ar * 32 + akb + 8] = *(const uint4*)(Arow + k0 + 8);
        u16 tmp[8] __attribute__((aligned(16)));
        if (isf) {
            #pragma unroll
            for (int j = 0; j < 8; ++j) tmp[j] = f2bf(Bf[bcol0 + (size_t)(k0 + j) * D_]);
        } else {
            #pragma unroll
            for (int j = 0; j < 8; ++j) tmp[j] = Bu[bcol0 + (size_t)(k0 + j) * D_];
        }
        *(uint4*)&Bs[bn * 32 + bkb] = *(uint4*)tmp;
        __syncthreads();

        const int mbase = wave * 32;
        bf16x8 af0 = *(const bf16x8*)&As[(mbase +      lr) * 32 + quad * 8];
        bf16x8 af1 = *(const bf16x8*)&As[(mbase + 16 + lr) * 32 + quad * 8];
        #pragma unroll
        for (int nt = 0; nt < 4; ++nt) {
            bf16x8 bf = *(const bf16x8*)&Bs[(nt * 16 + lr) * 32 + quad * 8];
            acc[0][nt] = __builtin_amdgcn_mfma_f32_16x16x32_bf16(af0, bf, acc[0][nt], 0, 0, 0);
            acc[1][nt] = __builtin_amdgcn_mfma_f32_16x16x32_bf16(af1, bf, acc[1][nt], 0, 0, 0);
        }
        __syncthreads();
    }

    #pragma unroll
    for (int s2 = 0; s2 < 2; ++s2) {
        #pragma unroll
        for (int nt = 0; nt < 4; ++nt) {
            const int ncol = ntile + nt * 16 + lr;
            const float bv = isf ? ((const float*)biasraw)[ncol]
                                 : bf2f(((const u16*)biasraw)[ncol]);
            #pragma unroll
            for (int r = 0; r < 4; ++r) {
                const int mrow = mtile + wave * 32 + s2 * 16 + quad * 4 + r;
                float v = acc[s2][nt][r] + bv;
                if (mode == 2) {
                    const float other = __shfl_xor(v, 1);
                    const int d = ncol & (DH - 1);
                    const int t = mrow & (T_ - 1);
                    const int i = d >> 1;
                    const float inv = exp2f(-(float)i * 0.41524101186092f);
                    const float ang = (float)t * inv;
                    const float cv = cosf(ang), sv = sinf(ang);
                    v = (d & 1) ? (other * sv + v * cv) : (v * cv - other * sv);
                }
                const int d  = ncol & (DH - 1);
                const int hh = ncol >> 6;
                const int t  = mrow & (T_ - 1);
                const int bb = mrow >> 11;
                if (mode == 0) {
                    if (isf) ((float*)out)[(size_t)mrow * D_ + ncol] = v;
                    else     ((u16*)out)[(size_t)mrow * D_ + ncol] = f2bf(v);
                } else if (mode == 1) {
                    // V^T: (N,H,DH,T)
                    ((u16*)out)[(((size_t)(bb * H_ + hh) * DH) + d) * T_ + t] = f2bf(v);
                } else {
                    ((u16*)out)[(((size_t)(bb * H_ + hh) * T_) + t) * DH + d] = f2bf(v);
                }
            }
        }
    }
}

// ---------------------------------------------------------------- attention
// MFMA flash attention. Block = 256 thr (4 waves) = one 64-row Q tile of one
// (b,h). Wave w owns Q-rows w*16..w*16+15. Per 64-key tile:
//   QK^T: 8 mfma 16x16x32 (A=Q frag regs, B=K frag from LDS)
//   softmax in C-layout regs (key=lane&15, qrow=quad*4+r), tanh soft-cap
//   P -> LDS (bf16, C-layout scatter) -> A-layout ds_read_b128
//   PV:  8 mfma (B=V^T frag from LDS: Vt[dim][key], key contiguous)
__global__ __launch_bounds__(256) void attn_kernel(const u16* __restrict__ Q,
                                                   const u16* __restrict__ K,
                                                   const u16* __restrict__ Vt,
                                                   const void* __restrict__ lensraw,
                                                   u16* __restrict__ ctx) {
    __shared__ __align__(16) u16 Ps[64 * PSTR];   // Q staging, then P tile
    __shared__ __align__(16) u16 Ks[64 * PSTR];
    __shared__ __align__(16) u16 Vts[64 * PSTR];  // [dim][key]

    const int tid  = threadIdx.x;
    const int wave = tid >> 6;
    const int lane = tid & 63;
    const int quad = lane >> 4;
    const int lr   = lane & 15;
    const int bh   = blockIdx.y;
    const int qs   = blockIdx.x * 64;
    const int b    = bh >> 4;
    const int hh   = bh & 15;
    const int len  = read_len(lensraw, b);
    const size_t base = (size_t)bh * T_ * DH;   // same for K (t,dh) and Vt (dh,t)

    const int srow = tid >> 2;            // staging row 0..63
    const int scb  = (tid & 3) * 16;      // staging col base

    // stage Q into Ps buffer, preload A-frags to registers
    *(uint4*)&Ps[srow * PSTR + scb]     = *(const uint4*)&Q[base + (size_t)(qs + srow) * DH + scb];
    *(uint4*)&Ps[srow * PSTR + scb + 8] = *(const uint4*)&Q[base + (size_t)(qs + srow) * DH + scb + 8];
    __syncthreads();
    const bf16x8 qa0 = *(const bf16x8*)&Ps[(wave * 16 + lr) * PSTR + quad * 8];
    const bf16x8 qa1 = *(const bf16x8*)&Ps[(wave * 16 + lr) * PSTR + 32 + quad * 8];

    f32x4 acc[4];
    float m[4], l[4];
    #pragma unroll
    for (int nt = 0; nt < 4; ++nt) acc[nt] = (f32x4){0.f, 0.f, 0.f, 0.f};
    #pragma unroll
    for (int r = 0; r < 4; ++r) { m[r] = MASK_NEG; l[r] = 0.f; }

    const int smax = min(qs + 63, len - 1);
    const int ktn  = smax / 64 + 1;

    for (int kt = 0; kt < ktn; ++kt) {
        const int ks = kt * 64;
        __syncthreads();   // previous PV reads (Vts) / P reads done
        // stage K tile [key][dim] and Vt tile [dim][key]
        *(uint4*)&Ks[srow * PSTR + scb]      = *(const uint4*)&K[base + (size_t)(ks + srow) * DH + scb];
        *(uint4*)&Ks[srow * PSTR + scb + 8]  = *(const uint4*)&K[base + (size_t)(ks + srow) * DH + scb + 8];
        *(uint4*)&Vts[srow * PSTR + scb]     = *(const uint4*)&Vt[base + (size_t)srow * T_ + ks + scb];
        *(uint4*)&Vts[srow * PSTR + scb + 8] = *(const uint4*)&Vt[base + (size_t)srow * T_ + ks + scb + 8];
        __syncthreads();

        // QK^T
        f32x4 s[4];
        #pragma unroll
        for (int nt = 0; nt < 4; ++nt) s[nt] = (f32x4){0.f, 0.f, 0.f, 0.f};
        #pragma unroll
        for (int nt = 0; nt < 4; ++nt) {
            bf16x8 kb0 = *(const bf16x8*)&Ks[(nt * 16 + lr) * PSTR + quad * 8];
            bf16x8 kb1 = *(const bf16x8*)&Ks[(nt * 16 + lr) * PSTR + 32 + quad * 8];
            s[nt] = __builtin_amdgcn_mfma_f32_16x16x32_bf16(qa0, kb0, s[nt], 0, 0, 0);
            s[nt] = __builtin_amdgcn_mfma_f32_16x16x32_bf16(qa1, kb1, s[nt], 0, 0, 0);
        }

        // softmax (C-layout). Row r: qrow = wave*16+quad*4+r, key = ks+nt*16+lr
        #pragma unroll
        for (int r = 0; r < 4; ++r) {
            const int trow = qs + wave * 16 + quad * 4 + r;
            float sc[4], mx = MASK_NEG;
            #pragma unroll
            for (int nt = 0; nt < 4; ++nt) {
                const float x = s[nt][r] * 0.125f;               // /sqrt(64)
                const float z = __expf(x * (2.0f / 30.0f));      // e^{2x/30}
                float t = 30.0f * (1.0f - 2.0f / (z + 1.0f));    // 30*tanh(x/30)
                const int col = ks + nt * 16 + lr;
                t = (col > trow || col >= len) ? MASK_NEG : t;
                sc[nt] = t;
                mx = fmaxf(mx, t);
            }
            #pragma unroll
            for (int off = 1; off < 16; off <<= 1) mx = fmaxf(mx, __shfl_xor(mx, off));
            const float mn = fmaxf(m[r], mx);
            float p[4], ps = 0.f;
            #pragma unroll
            for (int nt = 0; nt < 4; ++nt) { p[nt] = __expf(sc[nt] - mn); ps += p[nt]; }
            #pragma unroll
            for (int off = 1; off < 16; off <<= 1) ps += __shfl_xor(ps, off);
            const float alpha = __expf(m[r] - mn);
            m[r] = mn;
            l[r] = l[r] * alpha + ps;
            #pragma unroll
            for (int nt = 0; nt < 4; ++nt) {
                acc[nt][r] *= alpha;
                Ps[(wave * 16 + quad * 4 + r) * PSTR + nt * 16 + lr] = (u16)f2bf(p[nt]);
            }
        }
        __syncthreads();   // P visible to whole wave-row readers

        // PV
        bf16x8 pa0 = *(const bf16x8*)&Ps[(wave * 16 + lr) * PSTR + quad * 8];
        bf16x8 pa1 = *(const bf16x8*)&Ps[(wave * 16 + lr) * PSTR + 32 + quad * 8];
        #pragma unroll
        for (int nt = 0; nt < 4; ++nt) {
            bf16x8 vb0 = *(const bf16x8*)&Vts[(nt * 16 + lr) * PSTR + quad * 8];
            bf16x8 vb1 = *(const bf16x8*)&Vts[(nt * 16 + lr) * PSTR + 32 + quad * 8];
            acc[nt] = __builtin_amdgcn_mfma_f32_16x16x32_bf16(pa0, vb0, acc[nt], 0, 0, 0);
            acc[nt] = __builtin_amdgcn_mfma_f32_16x16x32_bf16(pa1, vb1, acc[nt], 0, 0, 0);
        }
    }

    // epilogue: ctx (N,T,H*DH) bf16
    #pragma unroll
    for (int r = 0; r < 4; ++r) {
        const float invl = (l[r] > 0.f) ? (1.0f / l[r]) : 0.f;
        const int qrow = wave * 16 + quad * 4 + r;
        #pragma unroll
        for (int nt = 0; nt < 4; ++nt) {
            ctx[(size_t)(b * T_ + qs + qrow) * D_ + hh * DH + nt * 16 + lr] =
                f2bf(acc[nt][r] * invl);
        }
    }
}

// ---------------------------------------------------------------- launch
extern "C" void kernel_launch(void* const* d_in, const int* in_sizes, int n_in,
                              void* d_out, int out_size, void* d_ws, size_t ws_size,
                              hipStream_t stream) {
    // ws layout (64 MB): [h: 16MB][q: 16MB][k: 16MB][vt: 16MB]
    u16* h = (u16*)d_ws;
    const size_t MD = (size_t)M_ * D_;
    u16* q  = h + MD;
    u16* k  = q + MD;
    u16* vt = k + MD;

    ln_kernel<<<M_, 256, 0, stream>>>(d_in[0], d_in[1], d_in[2], h);

    dim3 ggrid(D_ / 64, M_ / 128);
    gemm_kernel<<<ggrid, 256, 0, stream>>>(h, d_in[3], d_in[4], q, 2);
    gemm_kernel<<<ggrid, 256, 0, stream>>>(h, d_in[5], d_in[6], k, 2);
    gemm_kernel<<<ggrid, 256, 0, stream>>>(h, d_in[7], d_in[8], vt, 1);

    attn_kernel<<<dim3(T_ / 64, NB * H_), 256, 0, stream>>>(q, k, vt, d_in[13], h);

    gemm_kernel<<<ggrid, 256, 0, stream>>>(h, d_in[9], d_in[10], d_out, 0);
}

// Round 5
// 484.253 us; speedup vs baseline: 3.6515x; 1.2421x over previous
//
#include <hip/hip_runtime.h>
#include <hip/hip_bf16.h>

typedef unsigned short u16;
typedef unsigned int   u32;
typedef __bf16 bf16x8 __attribute__((ext_vector_type(8)));
typedef float  f32x4  __attribute__((ext_vector_type(4)));

#define NB 4
#define T_ 2048
#define D_ 1024
#define H_ 16
#define DH 64
#define M_ (NB * T_)   // 8192 rows
#define PSTR 72        // padded LDS row stride (elements) for 64-wide tiles

__device__ __forceinline__ float bf2f(u16 u) {
    union { u32 i; float f; } v; v.i = ((u32)u) << 16; return v.f;
}
__device__ __forceinline__ u16 f2bf(float f) {
    union { float fl; u32 i; } v; v.fl = f;
    u32 r = v.i + 0x7fff + ((v.i >> 16) & 1);
    return (u16)(r >> 16);
}

// ---------------------------------------------------------- dtype detector
__device__ __forceinline__ int detect_f32(const u16* p) {
    int weird = 0;
    const int lane = threadIdx.x & 63;
    #pragma unroll
    for (int i = 0; i < 4; ++i) {
        const u16 u = p[lane * 4 + i];
        const int e = (u >> 7) & 0xFF;
        weird += (e == 0xFF || (e >= 0x01 && e <= 0x3F) || (e >= 0xC0 && e <= 0xFE));
    }
    #pragma unroll
    for (int off = 32; off; off >>= 1) weird += __shfl_xor(weird, off);
    return weird >= 16;
}

// int32/int64-tolerant sequence-length read
__device__ __forceinline__ int read_len(const void* raw, int b) {
    const int* a32 = (const int*)raw;
    bool ok32 = true;
    #pragma unroll
    for (int i = 0; i < NB; ++i) {
        const int v = a32[i];
        if (v < 1 || v > T_) ok32 = false;
    }
    int v = ok32 ? a32[b] : (int)((const long long*)raw)[b];
    return min(max(v, 1), T_);
}

// ---------------------------------------------------------------- LayerNorm
__global__ __launch_bounds__(256) void ln_kernel(const void* __restrict__ xraw,
                                                 const void* __restrict__ graw,
                                                 const void* __restrict__ braw,
                                                 u16* __restrict__ h) {
    const int row = blockIdx.x;
    const int tid = threadIdx.x;
    const int isf = detect_f32((const u16*)xraw);

    float xv[4];
    if (isf) {
        const float* xr = (const float*)xraw + (size_t)row * D_;
        *(float4*)xv = *(const float4*)&xr[tid * 4];
    } else {
        const u16* xr = (const u16*)xraw + (size_t)row * D_;
        u16 loc[4] __attribute__((aligned(8)));
        *(uint2*)loc = *(const uint2*)&xr[tid * 4];
        #pragma unroll
        for (int i = 0; i < 4; ++i) xv[i] = bf2f(loc[i]);
    }

    float s = xv[0] + xv[1] + xv[2] + xv[3];
    float q = xv[0]*xv[0] + xv[1]*xv[1] + xv[2]*xv[2] + xv[3]*xv[3];

    #pragma unroll
    for (int off = 32; off; off >>= 1) {
        s += __shfl_xor(s, off);
        q += __shfl_xor(q, off);
    }
    __shared__ float red[8];
    const int wave = tid >> 6, lane = tid & 63;
    if (lane == 0) { red[wave] = s; red[4 + wave] = q; }
    __syncthreads();
    s = red[0] + red[1] + red[2] + red[3];
    q = red[4] + red[5] + red[6] + red[7];

    const float mean = s * (1.0f / D_);
    const float var  = q * (1.0f / D_) - mean * mean;
    const float rs   = rsqrtf(var + 1e-5f);

    u16 o[4] __attribute__((aligned(8)));
    #pragma unroll
    for (int i = 0; i < 4; ++i) {
        const int c = tid * 4 + i;
        const float gv = isf ? ((const float*)graw)[c] : bf2f(((const u16*)graw)[c]);
        const float bv = isf ? ((const float*)braw)[c] : bf2f(((const u16*)braw)[c]);
        o[i] = f2bf((xv[i] - mean) * rs * gv + bv);
    }
    *(uint2*)&h[(size_t)row * D_ + tid * 4] = *(uint2*)o;
}

// ------------------------------------------------- weight transpose+convert
// Wt[n][k] (bf16) from W[k][n] (f32 or bf16). 64x64 tiles via LDS.
__global__ __launch_bounds__(256) void wconv_kernel(const void* __restrict__ Wraw,
                                                    u16* __restrict__ Wt) {
    __shared__ u16 tile[64][PSTR];
    const int isf = detect_f32((const u16*)Wraw);
    const int n0 = blockIdx.x * 64;
    const int k0 = blockIdx.y * 64;
    const int tid = threadIdx.x;
    const int tr  = tid >> 2;          // 0..63
    const int tc  = (tid & 3) * 16;    // 0,16,32,48

    if (isf) {
        const float* W = (const float*)Wraw;
        #pragma unroll
        for (int i = 0; i < 16; ++i)
            tile[tc + i][tr] = f2bf(W[(size_t)(k0 + tr) * D_ + n0 + tc + i]);
    } else {
        const u16* W = (const u16*)Wraw;
        #pragma unroll
        for (int i = 0; i < 16; ++i)
            tile[tc + i][tr] = W[(size_t)(k0 + tr) * D_ + n0 + tc + i];
    }
    __syncthreads();
    *(uint4*)&Wt[(size_t)(n0 + tr) * D_ + k0 + tc]     = *(uint4*)&tile[tr][tc];
    *(uint4*)&Wt[(size_t)(n0 + tr) * D_ + k0 + tc + 8] = *(uint4*)&tile[tr][tc + 8];
}

// ---------------------------------------------------------------- GEMM
// mode 0: row-major store to d_out (format follows weight dtype)
// mode 1: scatter V TRANSPOSED (N,H,DH,T)
// mode 2: scatter (N,H,T,DH) + RoPE (Q,K)
// Bt != nullptr: pre-transposed bf16 weights [n][k] (fast staging path).
__global__ __launch_bounds__(256) void gemm_kernel(const u16* __restrict__ A,
                                                   const void* __restrict__ Braw,
                                                   const u16* __restrict__ Bt,
                                                   const void* __restrict__ biasraw,
                                                   void* __restrict__ out,
                                                   const int mode) {
    __shared__ __align__(16) u16 As[128 * 32];
    __shared__ __align__(16) u16 Bs[64 * 32];

    const int tid   = threadIdx.x;
    const int ntile = blockIdx.x * 64;
    const int mtile = blockIdx.y * 128;
    const int wave  = tid >> 6;
    const int lane  = tid & 63;
    const int quad  = lane >> 4;
    const int lr    = lane & 15;

    const int isf = detect_f32((const u16*)Braw);
    const float* Bf = (const float*)Braw;
    const u16*   Bu = (const u16*)Braw;

    f32x4 acc[2][4];
    #pragma unroll
    for (int s = 0; s < 2; ++s)
        #pragma unroll
        for (int n = 0; n < 4; ++n)
            acc[s][n] = (f32x4){0.f, 0.f, 0.f, 0.f};

    const int ar  = tid >> 1;
    const int akb = (tid & 1) * 16;
    const int bn  = tid & 63;
    const int bkb = (tid >> 6) * 8;
    const int br  = tid >> 2;           // fast path: B row 0..63
    const int bk2 = (tid & 3) * 8;      // fast path: k chunk
    const u16* Arow = A + (size_t)(mtile + ar) * D_ + akb;
    const size_t bcol0 = (size_t)bkb * D_ + ntile + bn;
    const u16* Btrow = Bt ? (Bt + (size_t)(ntile + br) * D_ + bk2) : nullptr;

    for (int k0 = 0; k0 < D_; k0 += 32) {
        *(uint4*)&As[ar * 32 + akb]     = *(const uint4*)(Arow + k0);
        *(uint4*)&As[ar * 32 + akb + 8] = *(const uint4*)(Arow + k0 + 8);
        if (Bt) {
            *(uint4*)&Bs[br * 32 + bk2] = *(const uint4*)(Btrow + k0);
        } else {
            u16 tmp[8] __attribute__((aligned(16)));
            if (isf) {
                #pragma unroll
                for (int j = 0; j < 8; ++j) tmp[j] = f2bf(Bf[bcol0 + (size_t)(k0 + j) * D_]);
            } else {
                #pragma unroll
                for (int j = 0; j < 8; ++j) tmp[j] = Bu[bcol0 + (size_t)(k0 + j) * D_];
            }
            *(uint4*)&Bs[bn * 32 + bkb] = *(uint4*)tmp;
        }
        __syncthreads();

        const int mbase = wave * 32;
        bf16x8 af0 = *(const bf16x8*)&As[(mbase +      lr) * 32 + quad * 8];
        bf16x8 af1 = *(const bf16x8*)&As[(mbase + 16 + lr) * 32 + quad * 8];
        #pragma unroll
        for (int nt = 0; nt < 4; ++nt) {
            bf16x8 bf = *(const bf16x8*)&Bs[(nt * 16 + lr) * 32 + quad * 8];
            acc[0][nt] = __builtin_amdgcn_mfma_f32_16x16x32_bf16(af0, bf, acc[0][nt], 0, 0, 0);
            acc[1][nt] = __builtin_amdgcn_mfma_f32_16x16x32_bf16(af1, bf, acc[1][nt], 0, 0, 0);
        }
        __syncthreads();
    }

    #pragma unroll
    for (int s2 = 0; s2 < 2; ++s2) {
        #pragma unroll
        for (int nt = 0; nt < 4; ++nt) {
            const int ncol = ntile + nt * 16 + lr;
            const float bv = isf ? ((const float*)biasraw)[ncol]
                                 : bf2f(((const u16*)biasraw)[ncol]);
            #pragma unroll
            for (int r = 0; r < 4; ++r) {
                const int mrow = mtile + wave * 32 + s2 * 16 + quad * 4 + r;
                float v = acc[s2][nt][r] + bv;
                if (mode == 2) {
                    const float other = __shfl_xor(v, 1);
                    const int d = ncol & (DH - 1);
                    const int t = mrow & (T_ - 1);
                    const int i = d >> 1;
                    const float inv = exp2f(-(float)i * 0.41524101186092f);
                    const float ang = (float)t * inv;
                    const float cv = cosf(ang), sv = sinf(ang);
                    v = (d & 1) ? (other * sv + v * cv) : (v * cv - other * sv);
                }
                const int d  = ncol & (DH - 1);
                const int hh = ncol >> 6;
                const int t  = mrow & (T_ - 1);
                const int bb = mrow >> 11;
                if (mode == 0) {
                    if (isf) ((float*)out)[(size_t)mrow * D_ + ncol] = v;
                    else     ((u16*)out)[(size_t)mrow * D_ + ncol] = f2bf(v);
                } else if (mode == 1) {
                    ((u16*)out)[(((size_t)(bb * H_ + hh) * DH) + d) * T_ + t] = f2bf(v);
                } else {
                    ((u16*)out)[(((size_t)(bb * H_ + hh) * T_) + t) * DH + d] = f2bf(v);
                }
            }
        }
    }
}

// ---------------------------------------------------------------- attention
// MFMA flash attention, FIXED-MAX softmax.
// Soft-cap bounds scores to [-30,30], so use constant max 30:
//   p = exp(30*tanh(x/30) - 30) = exp(-60/(z+1)),  z = exp(s/120)
// (s = raw QK^T MFMA value; /sqrt(64) folded into the 1/120). No running max,
// no alpha rescale, no per-tile shuffle reductions; l accumulated per-lane,
// reduced once at the end. NaN-free: z=inf -> p=1, z=0 -> p=e^-60.
__global__ __launch_bounds__(256) void attn_kernel(const u16* __restrict__ Q,
                                                   const u16* __restrict__ K,
                                                   const u16* __restrict__ Vt,
                                                   const void* __restrict__ lensraw,
                                                   u16* __restrict__ ctx) {
    __shared__ __align__(16) u16 Ps[64 * PSTR];   // Q staging, then P tile
    __shared__ __align__(16) u16 Ks[64 * PSTR];
    __shared__ __align__(16) u16 Vts[64 * PSTR];  // [dim][key]

    const int tid  = threadIdx.x;
    const int wave = tid >> 6;
    const int lane = tid & 63;
    const int quad = lane >> 4;
    const int lr   = lane & 15;
    const int bh   = blockIdx.y;
    const int qs   = blockIdx.x * 64;
    const int b    = bh >> 4;
    const int hh   = bh & 15;
    const int len  = read_len(lensraw, b);
    const size_t base = (size_t)bh * T_ * DH;

    const int srow = tid >> 2;
    const int scb  = (tid & 3) * 16;

    *(uint4*)&Ps[srow * PSTR + scb]     = *(const uint4*)&Q[base + (size_t)(qs + srow) * DH + scb];
    *(uint4*)&Ps[srow * PSTR + scb + 8] = *(const uint4*)&Q[base + (size_t)(qs + srow) * DH + scb + 8];
    __syncthreads();
    const bf16x8 qa0 = *(const bf16x8*)&Ps[(wave * 16 + lr) * PSTR + quad * 8];
    const bf16x8 qa1 = *(const bf16x8*)&Ps[(wave * 16 + lr) * PSTR + 32 + quad * 8];

    f32x4 acc[4];
    float l_loc[4] = {0.f, 0.f, 0.f, 0.f};
    #pragma unroll
    for (int nt = 0; nt < 4; ++nt) acc[nt] = (f32x4){0.f, 0.f, 0.f, 0.f};

    const int smax = min(qs + 63, len - 1);
    const int ktn  = smax / 64 + 1;

    for (int kt = 0; kt < ktn; ++kt) {
        const int ks = kt * 64;
        __syncthreads();   // previous tile's MFMA reads of Ks/Vts done
        *(uint4*)&Ks[srow * PSTR + scb]      = *(const uint4*)&K[base + (size_t)(ks + srow) * DH + scb];
        *(uint4*)&Ks[srow * PSTR + scb + 8]  = *(const uint4*)&K[base + (size_t)(ks + srow) * DH + scb + 8];
        *(uint4*)&Vts[srow * PSTR + scb]     = *(const uint4*)&Vt[base + (size_t)srow * T_ + ks + scb];
        *(uint4*)&Vts[srow * PSTR + scb + 8] = *(const uint4*)&Vt[base + (size_t)srow * T_ + ks + scb + 8];
        __syncthreads();

        // QK^T
        f32x4 s[4];
        #pragma unroll
        for (int nt = 0; nt < 4; ++nt) s[nt] = (f32x4){0.f, 0.f, 0.f, 0.f};
        #pragma unroll
        for (int nt = 0; nt < 4; ++nt) {
            bf16x8 kb0 = *(const bf16x8*)&Ks[(nt * 16 + lr) * PSTR + quad * 8];
            bf16x8 kb1 = *(const bf16x8*)&Ks[(nt * 16 + lr) * PSTR + 32 + quad * 8];
            s[nt] = __builtin_amdgcn_mfma_f32_16x16x32_bf16(qa0, kb0, s[nt], 0, 0, 0);
            s[nt] = __builtin_amdgcn_mfma_f32_16x16x32_bf16(qa1, kb1, s[nt], 0, 0, 0);
        }

        // fixed-max softmax (C-layout: qrow = wave*16+quad*4+r, key = ks+nt*16+lr)
        #pragma unroll
        for (int r = 0; r < 4; ++r) {
            const int trow = qs + wave * 16 + quad * 4 + r;
            #pragma unroll
            for (int nt = 0; nt < 4; ++nt) {
                const float z = __expf(s[nt][r] * (1.0f / 120.0f));
                float p = __expf(-60.0f * __builtin_amdgcn_rcpf(z + 1.0f));
                const int col = ks + nt * 16 + lr;
                p = (col > trow || col >= len) ? 0.f : p;
                l_loc[r] += p;
                Ps[(wave * 16 + quad * 4 + r) * PSTR + nt * 16 + lr] = f2bf(p);
            }
        }
        __syncthreads();

        // PV
        bf16x8 pa0 = *(const bf16x8*)&Ps[(wave * 16 + lr) * PSTR + quad * 8];
        bf16x8 pa1 = *(const bf16x8*)&Ps[(wave * 16 + lr) * PSTR + 32 + quad * 8];
        #pragma unroll
        for (int nt = 0; nt < 4; ++nt) {
            bf16x8 vb0 = *(const bf16x8*)&Vts[(nt * 16 + lr) * PSTR + quad * 8];
            bf16x8 vb1 = *(const bf16x8*)&Vts[(nt * 16 + lr) * PSTR + 32 + quad * 8];
            acc[nt] = __builtin_amdgcn_mfma_f32_16x16x32_bf16(pa0, vb0, acc[nt], 0, 0, 0);
            acc[nt] = __builtin_amdgcn_mfma_f32_16x16x32_bf16(pa1, vb1, acc[nt], 0, 0, 0);
        }
    }

    // epilogue: reduce l across the 16 lanes of each row group, write ctx
    #pragma unroll
    for (int r = 0; r < 4; ++r) {
        float l = l_loc[r];
        #pragma unroll
        for (int off = 1; off < 16; off <<= 1) l += __shfl_xor(l, off);
        const float invl = (l > 0.f) ? (1.0f / l) : 0.f;
        const int qrow = wave * 16 + quad * 4 + r;
        #pragma unroll
        for (int nt = 0; nt < 4; ++nt) {
            ctx[(size_t)(b * T_ + qs + qrow) * D_ + hh * DH + nt * 16 + lr] =
                f2bf(acc[nt][r] * invl);
        }
    }
}

// ---------------------------------------------------------------- launch
extern "C" void kernel_launch(void* const* d_in, const int* in_sizes, int n_in,
                              void* d_out, int out_size, void* d_ws, size_t ws_size,
                              hipStream_t stream) {
    // ws layout: [h:16MB][q:16MB][k:16MB][vt:16MB][wtq|wtk|wtv|wto: 2MB each]
    u16* h = (u16*)d_ws;
    const size_t MD = (size_t)M_ * D_;
    const size_t WD = (size_t)D_ * D_;
    u16* q  = h + MD;
    u16* k  = q + MD;
    u16* vt = k + MD;
    const bool havewt = ws_size >= (4 * MD + 4 * WD) * sizeof(u16);
    u16* wtq = havewt ? (vt + MD)  : nullptr;
    u16* wtk = havewt ? (wtq + WD) : nullptr;
    u16* wtv = havewt ? (wtk + WD) : nullptr;
    u16* wto = havewt ? (wtv + WD) : nullptr;

    ln_kernel<<<M_, 256, 0, stream>>>(d_in[0], d_in[1], d_in[2], h);

    if (havewt) {
        dim3 wgrid(D_ / 64, D_ / 64);
        wconv_kernel<<<wgrid, 256, 0, stream>>>(d_in[3], wtq);
        wconv_kernel<<<wgrid, 256, 0, stream>>>(d_in[5], wtk);
        wconv_kernel<<<wgrid, 256, 0, stream>>>(d_in[7], wtv);
        wconv_kernel<<<wgrid, 256, 0, stream>>>(d_in[9], wto);
    }

    dim3 ggrid(D_ / 64, M_ / 128);
    gemm_kernel<<<ggrid, 256, 0, stream>>>(h, d_in[3], wtq, d_in[4], q, 2);
    gemm_kernel<<<ggrid, 256, 0, stream>>>(h, d_in[5], wtk, d_in[6], k, 2);
    gemm_kernel<<<ggrid, 256, 0, stream>>>(h, d_in[7], wtv, d_in[8], vt, 1);

    attn_kernel<<<dim3(T_ / 64, NB * H_), 256, 0, stream>>>(q, k, vt, d_in[13], h);

    gemm_kernel<<<ggrid, 256, 0, stream>>>(h, d_in[9], wto, d_in[10], d_out, 0);
}